// Round 9
// baseline (204.031 us; speedup 1.0000x reference)
//
#include <hip/hip_runtime.h>

typedef unsigned short u16;
typedef short bf16x8 __attribute__((ext_vector_type(8)));
typedef float f32x4 __attribute__((ext_vector_type(4)));

#define AS1 __attribute__((address_space(1)))
#define AS3 __attribute__((address_space(3)))

__device__ __forceinline__ u16 f2bf(float f) {
    unsigned u = __float_as_uint(f);
    u += 0x7fffu + ((u >> 16) & 1u);   // RNE
    return (u16)(u >> 16);
}
__device__ __forceinline__ float bf2f(u16 h) {
    return __uint_as_float(((unsigned)h) << 16);
}

__device__ __forceinline__ void gload_lds16(const void* g, void* l) {
    __builtin_amdgcn_global_load_lds((AS1 unsigned int*)(g),
                                     (AS3 unsigned int*)(l), 16, 0, 0);
}

// ---------------- stage 1: prep (W0/W1 cvt + Qt/E1 build) ----------------
__global__ void prep_kernel(const float* __restrict__ W0, const float* __restrict__ W1,
                            const float* __restrict__ x, const float* __restrict__ emb,
                            u16* __restrict__ W0b, u16* __restrict__ W1b,
                            u16* __restrict__ Qt, u16* __restrict__ E1) {
    int gid = blockIdx.x;
    if (gid < 4608) {                       // cvt W0 (4096 blocks) + W1 (512 blocks)
        int i = gid * 256 + threadIdx.x;
        const float* src; u16* dst; int j;
        if (i < 1048576) { src = W0; dst = W0b; j = i; }
        else             { src = W1; dst = W1b; j = i - 1048576; }
        float4 v = reinterpret_cast<const float4*>(src)[j];
        ushort4 o;
        o.x = f2bf(v.x); o.y = f2bf(v.y); o.z = f2bf(v.z); o.w = f2bf(v.w);
        reinterpret_cast<ushort4*>(dst)[j] = o;
    } else {                                // build Qt + E1: 1024 blocks x 4 n each
        int n = (gid - 4608) * 4 + (threadIdx.x >> 6);
        int lane = threadIdx.x & 63;
        int b = n >> 4, d = n & 15;
        int m0 = lane * 4;
        float4 xv = *reinterpret_cast<const float4*>(x + b * 256 + m0);
        ushort4 q;
        q.x = f2bf(xv.x * emb[(m0 + 0) * 16 + d]);
        q.y = f2bf(xv.y * emb[(m0 + 1) * 16 + d]);
        q.z = f2bf(xv.z * emb[(m0 + 2) * 16 + d]);
        q.w = f2bf(xv.w * emb[(m0 + 3) * 16 + d]);
        *reinterpret_cast<ushort4*>(Qt + n * 256 + m0) = q;
        // E1 pack: [ng 4][nt 2][wn 4][hh 2][wm 2][fm 4][fn 8][lane 64][e 4]
        // h=m0..m0+3: hh=(m0>>7), wm=(m0>>6)&1, fm=(m0>>4)&3, sl=(m0>>2)&3, e=m0&3
        // n: ng=n>>10, nt=(n>>9)&1, wn=(n>>7)&3, fn=(n>>4)&7, c=n&15; lane=sl*16+c
        int e1u4 = ((((((((n >> 10) * 2 + ((n >> 9) & 1)) * 4 + ((n >> 7) & 3)) * 2
                   + ((m0 >> 7) & 1)) * 2 + ((m0 >> 6) & 1)) * 4 + ((m0 >> 4) & 3)) * 8
                   + ((n >> 4) & 7)) * 64) + ((m0 >> 2) & 3) * 16 + (n & 15);
        *reinterpret_cast<ushort4*>(E1 + e1u4 * 4) = q;
    }
}

// ---------------- stage 2: layer 1 — persistent-A, 32-chunk stream ----------------
// grid 256 (= 64 o x 4 ng; 1 block/CU, single round), 512 thr = 8 waves (2wm x 4wn),
// wave tile 64h x 128n. A h-half [128][256] persistent in LDS; B [512n][32k] 2-buf depth-1.
__global__ __launch_bounds__(512, 1) void cin1_kernel(
    const u16* __restrict__ W0b, const u16* __restrict__ Qt, const u16* __restrict__ E1,
    const float* __restrict__ b0, u16* __restrict__ E2, float* __restrict__ S1)
{
    __shared__ __attribute__((aligned(16))) u16 ldsA[32768];       // [128 r][256 k] swz
    __shared__ __attribute__((aligned(16))) u16 ldsB[2][16384];    // [512 n][32 k]
    __shared__ float part[2][512];

    const int tid = threadIdx.x, lane = tid & 63, w = tid >> 6;
    const int wm = w >> 2, wn = w & 3;
    const int bid = blockIdx.x;
    const int o = (bid & 7) * 8 + ((bid >> 3) >> 2);   // 8 o's per XCD
    const int ng = (bid >> 3) & 3;

    // A stage: instr i covers rows i*16+(tid>>5), phys slot P=tid&31 holds logical
    // L = ((P&~3)^(r&4)) + ((P&3)^(r&3))  (involution; read side inverts)
    const int r7 = (tid >> 5) & 7;
    const int P = tid & 31;
    const int Ls = (((P >> 2) << 2) ^ (r7 & 4)) + ((P & 3) ^ (r7 & 3));
    const u16* aStage = W0b + (o * 256 + (tid >> 5)) * 256 + Ls * 8;  // +hh*32768 +i*4096
    // B stage: instr i covers rows i*128+(tid>>2), slot tid&3 (linear, no swizzle)
    const u16* bStage = Qt + (ng * 1024 + (tid >> 2)) * 256 + (tid & 3) * 8;
    // A frag read: row=wm*64+fm*16+(lane&15); phys=(4kt^(lane&4)) + ((lane>>4)^(lane&3))
    const int aRowPart = (wm * 64 + (lane & 15)) * 256 + (((lane >> 4) ^ (lane & 3)) << 3);
    const int aAdjE = aRowPart + ((lane & 4) << 3);   // even kt
    const int aAdjO = aRowPart - ((lane & 4) << 3);   // odd kt
    // B frag read: row=wn*128+fn*16+(lane&15), slot=lane>>4 (naturally conflict-free)
    const int bRd = (wn * 128 + (lane & 15)) * 32 + ((lane >> 4) << 3);

    f32x4 zero = {0.f, 0.f, 0.f, 0.f};
    f32x4 acc[4][8];
#pragma unroll
    for (int fm = 0; fm < 4; ++fm)
#pragma unroll
        for (int fn = 0; fn < 8; ++fn) acc[fm][fn] = zero;
    float psum[2][8] = {{0.f,0.f,0.f,0.f,0.f,0.f,0.f,0.f},{0.f,0.f,0.f,0.f,0.f,0.f,0.f,0.f}};

    auto stageA = [&](int hh) {
#pragma unroll
        for (int i = 0; i < 8; ++i)
            gload_lds16(aStage + hh * 32768 + i * 4096, &ldsA[i * 4096 + tid * 8]);
    };
    auto stageB = [&](int c1) {
        const int nt1 = (c1 >> 3) & 1, kt1 = c1 & 7, bb1 = c1 & 1;
#pragma unroll
        for (int i = 0; i < 4; ++i)
            gload_lds16(bStage + nt1 * 131072 + i * 32768 + kt1 * 32,
                        &ldsB[bb1][i * 4096 + tid * 8]);
    };

    stageA(0);
    stageB(0);
#pragma unroll
    for (int c = 0; c < 32; ++c) {
        const int kt = c & 7, nt = (c >> 3) & 1, hh = c >> 4, bb = c & 1;
        if (c == 16) {       // A-restage boundary: one extra drain+barrier
            asm volatile("s_waitcnt vmcnt(0)" ::: "memory");
            __builtin_amdgcn_s_barrier();
            asm volatile("" ::: "memory");
            stageA(1);
            stageB(17);
            asm volatile("s_waitcnt vmcnt(4)" ::: "memory");   // A landed; B(17) in flight
            __builtin_amdgcn_s_barrier();
            asm volatile("" ::: "memory");
        } else {
            asm volatile("s_waitcnt vmcnt(0)" ::: "memory");   // B(c) landed
            __builtin_amdgcn_s_barrier();
            asm volatile("" ::: "memory");
        }
        bf16x8 aF[4], bF[8];
        const int aBase = ((kt & 1) ? aAdjO : aAdjE) + kt * 32;
#pragma unroll
        for (int fm = 0; fm < 4; ++fm)
            aF[fm] = *reinterpret_cast<const bf16x8*>(&ldsA[aBase + fm * 4096]);
#pragma unroll
        for (int fn = 0; fn < 8; ++fn)
            bF[fn] = *reinterpret_cast<const bf16x8*>(&ldsB[bb][bRd + fn * 512]);
        if (c < 31 && c != 16) stageB(c + 1);    // other buffer; hidden under MFMAs
#pragma unroll
        for (int fm = 0; fm < 4; ++fm)
#pragma unroll
            for (int fn = 0; fn < 8; ++fn)
                acc[fm][fn] = __builtin_amdgcn_mfma_f32_16x16x32_bf16(aF[fm], bF[fn], acc[fm][fn], 0, 0, 0);
        if ((c & 7) == 7) {  // fold h-reduction: psum[nt] += Q .* acc, reset acc
            const u16* eb = E1 + ((((ng * 2 + nt) * 4 + wn) * 2 + hh) * 2 + wm) * 8192 + lane * 4;
#pragma unroll
            for (int fm = 0; fm < 4; ++fm)
#pragma unroll
                for (int fn = 0; fn < 8; ++fn) {
                    ushort4 wv = *reinterpret_cast<const ushort4*>(eb + (fm * 8 + fn) * 256);
                    psum[nt][fn] += bf2f(wv.x) * acc[fm][fn][0] + bf2f(wv.y) * acc[fm][fn][1]
                                  + bf2f(wv.z) * acc[fm][fn][2] + bf2f(wv.w) * acc[fm][fn][3];
                    acc[fm][fn] = zero;
                }
        }
    }

    // final: cross-lane (h-subgroups) + cross-wm reduce, bias, relu, E2/S1
#pragma unroll
    for (int nt = 0; nt < 2; ++nt) {
        __syncthreads();
#pragma unroll
        for (int fn = 0; fn < 8; ++fn) {
            float p = psum[nt][fn];
            p += __shfl_xor(p, 16);
            p += __shfl_xor(p, 32);
            if (lane < 16) part[wm][wn * 128 + fn * 16 + lane] = p;
        }
        __syncthreads();
        {
            const int nl = tid;
            float v = part[0][nl] + part[1][nl] + b0[o];
            float r = fmaxf(v, 0.0f);
            const int n = ng * 1024 + nt * 512 + nl;
            if (o < 32) {
                E2[(n >> 4) * 512 + (n & 15) * 32 + o] = f2bf(r);   // [n/16][c 16][h 32]
            } else {
                float s = r;
                s += __shfl_xor(s, 1); s += __shfl_xor(s, 2);
                s += __shfl_xor(s, 4); s += __shfl_xor(s, 8);
                if ((n & 15) == 0) S1[(n >> 4) * 32 + (o - 32)] = s;
            }
        }
    }
}

// ---------------- stage 3: layer 2 (R5 structure, unchanged/passing) ----------------
__global__ __launch_bounds__(256, 4) void cin2_kernel(
    const u16* __restrict__ W1b, const u16* __restrict__ Qt, const u16* __restrict__ E2,
    const float* __restrict__ b1, float* __restrict__ S2)
{
    __shared__ __attribute__((aligned(16))) u16 As[3][4096];   // 128r x 32k
    __shared__ __attribute__((aligned(16))) u16 Bs[3][4096];
    __shared__ float part[2][2][128];

    const int tid = threadIdx.x, lane = tid & 63, w = tid >> 6;
    const int wh = w >> 1, wn = w & 1;
    const int bid = blockIdx.x;
    const int g8 = bid & 7, rest = bid >> 3;     // 0..63
    const int og = g8 * 2 + (rest & 1);          // 0..15
    const int ntile = rest >> 1;                 // 0..31

    const int rl = lane >> 2;
    const int sw = ((lane & 3) ^ ((rl + (rl >> 2)) & 3)) << 3;
    const u16* aS0 = W1b + (og * 128 + (w * 2 + 0) * 16 + rl) * 256 + sw;
    const u16* aS1 = W1b + (og * 128 + (w * 2 + 1) * 16 + rl) * 256 + sw;
    const u16* bS0 = Qt + (ntile * 128 + (w * 2 + 0) * 16 + rl) * 256 + sw;
    const u16* bS1 = Qt + (ntile * 128 + (w * 2 + 1) * 16 + rl) * 256 + sw;
    const int ldsI0 = (w * 2 + 0) * 512, ldsI1 = (w * 2 + 1) * 512;

    const int rbA = wh * 64 + (lane & 15);
    const int rbB = wn * 64 + (lane & 15);
    const int sl = lane >> 4;
    const int aOff = rbA * 32 + ((sl ^ ((rbA + (rbA >> 2)) & 3)) << 3);
    const int bOff = rbB * 32 + ((sl ^ ((rbB + (rbB >> 2)) & 3)) << 3);

    f32x4 zero = {0.f, 0.f, 0.f, 0.f};
    f32x4 acc[4][4];
#pragma unroll
    for (int f = 0; f < 4; ++f)
#pragma unroll
        for (int gg = 0; gg < 4; ++gg) acc[f][gg] = zero;

    auto stage = [&](int kc, int bb) {
        int ko = kc * 32;
        gload_lds16(aS0 + ko, &As[bb][ldsI0]);
        gload_lds16(aS1 + ko, &As[bb][ldsI1]);
        gload_lds16(bS0 + ko, &Bs[bb][ldsI0]);
        gload_lds16(bS1 + ko, &Bs[bb][ldsI1]);
    };

    stage(0, 0); stage(1, 1);
#pragma unroll
    for (int kc = 0; kc < 8; ++kc) {
        if (kc < 7) asm volatile("s_waitcnt vmcnt(4)" ::: "memory");
        else        asm volatile("s_waitcnt vmcnt(0)" ::: "memory");
        __builtin_amdgcn_s_barrier();
        asm volatile("" ::: "memory");
        if (kc < 6) stage(kc + 2, (kc + 2) % 3);
        const u16* Ab = &As[kc % 3][0];
        const u16* Bb = &Bs[kc % 3][0];
        bf16x8 a[4], b[4];
#pragma unroll
        for (int f = 0; f < 4; ++f)
            a[f] = *reinterpret_cast<const bf16x8*>(Ab + aOff + f * 512);
#pragma unroll
        for (int gg = 0; gg < 4; ++gg)
            b[gg] = *reinterpret_cast<const bf16x8*>(Bb + bOff + gg * 512);
        __builtin_amdgcn_s_setprio(1);
#pragma unroll
        for (int f = 0; f < 4; ++f)
#pragma unroll
            for (int gg = 0; gg < 4; ++gg)
                acc[f][gg] = __builtin_amdgcn_mfma_f32_16x16x32_bf16(a[f], b[gg], acc[f][gg], 0, 0, 0);
        __builtin_amdgcn_s_setprio(0);
    }

    float psum[2][4] = {{0.f,0.f,0.f,0.f},{0.f,0.f,0.f,0.f}};
    const u16* eb = E2 + (ntile * 2 + wn) * 2048 + (lane & 15) * 32 + (lane >> 4) * 4;
#pragma unroll
    for (int f = 0; f < 4; ++f)
#pragma unroll
        for (int gg = 0; gg < 4; ++gg) {
            ushort4 wv = *reinterpret_cast<const ushort4*>(eb + gg * 512 + (f & 1) * 16);
            psum[f >> 1][gg] += bf2f(wv.x) * acc[f][gg][0] + bf2f(wv.y) * acc[f][gg][1]
                              + bf2f(wv.z) * acc[f][gg][2] + bf2f(wv.w) * acc[f][gg][3];
        }
#pragma unroll
    for (int ol = 0; ol < 2; ++ol)
#pragma unroll
        for (int gg = 0; gg < 4; ++gg) {
            float p = psum[ol][gg];
            p += __shfl_xor(p, 16);
            p += __shfl_xor(p, 32);
            if (lane < 16) part[wh][ol][wn * 64 + gg * 16 + lane] = p;
        }
    __syncthreads();
    if (tid < 128) {
        const int nl = tid;
        const int n = ntile * 128 + nl;
#pragma unroll
        for (int o4 = 0; o4 < 4; ++o4) {
            const int oo = og * 4 + o4;
            float v = part[o4 >> 1][o4 & 1][nl] + b1[oo];
            float r = fmaxf(v, 0.0f);
            float s = r;
            s += __shfl_xor(s, 1); s += __shfl_xor(s, 2);
            s += __shfl_xor(s, 4); s += __shfl_xor(s, 8);
            if ((nl & 15) == 0) S2[(n >> 4) * 64 + oo] = s;
        }
    }
}

// ---------------- stage 4: final FC ----------------
__global__ void final_fc_kernel(const float* __restrict__ S1, const float* __restrict__ S2,
                                const float* __restrict__ fcW, const float* __restrict__ fcb,
                                float* __restrict__ out) {
    int b = threadIdx.x;   // 256
    float a0 = fcb[0], a1 = fcb[1];
#pragma unroll 8
    for (int c = 0; c < 32; ++c) {
        float v = S1[b * 32 + c];
        a0 += v * fcW[c]; a1 += v * fcW[96 + c];
    }
#pragma unroll 8
    for (int c = 0; c < 64; ++c) {
        float v = S2[b * 64 + c];
        a0 += v * fcW[32 + c]; a1 += v * fcW[96 + 32 + c];
    }
    out[b * 2 + 0] = a0;
    out[b * 2 + 1] = a1;
}

extern "C" void kernel_launch(void* const* d_in, const int* in_sizes, int n_in,
                              void* d_out, int out_size, void* d_ws, size_t ws_size,
                              hipStream_t stream) {
    const float* x   = (const float*)d_in[0];
    const float* emb = (const float*)d_in[1];
    const float* W0  = (const float*)d_in[2];
    const float* b0  = (const float*)d_in[3];
    const float* W1  = (const float*)d_in[4];
    const float* b1  = (const float*)d_in[5];
    const float* fcW = (const float*)d_in[6];
    const float* fcb = (const float*)d_in[7];
    float* out = (float*)d_out;

    char* ws = (char*)d_ws;
    u16*   W0b = (u16*)(ws);                 //  8,388,608 B
    u16*   W1b = (u16*)(ws + 8388608);       //  1,048,576 B
    u16*   Qt  = (u16*)(ws + 9437184);       //  2,097,152 B
    u16*   E1  = (u16*)(ws + 11534336);      //  2,097,152 B
    u16*   E2  = (u16*)(ws + 13631488);      //    262,144 B
    float* S1  = (float*)(ws + 13893632);    //     32,768 B
    float* S2  = (float*)(ws + 13926400);    //     65,536 B

    prep_kernel<<<5632, 256, 0, stream>>>(W0, W1, x, emb, W0b, W1b, Qt, E1);
    cin1_kernel<<<256, 512, 0, stream>>>(W0b, Qt, E1, b0, E2, S1);
    cin2_kernel<<<512, 256, 0, stream>>>(W1b, Qt, E2, b1, S2);
    final_fc_kernel<<<1, 256, 0, stream>>>(S1, S2, fcW, fcb, out);
}

// Round 10
// 83.971 us; speedup vs baseline: 2.4298x; 2.4298x over previous
//
#include <hip/hip_runtime.h>

typedef unsigned short u16;
typedef short bf16x8 __attribute__((ext_vector_type(8)));
typedef float f32x4 __attribute__((ext_vector_type(4)));

#define AS1 __attribute__((address_space(1)))
#define AS3 __attribute__((address_space(3)))

__device__ __forceinline__ u16 f2bf(float f) {
    unsigned u = __float_as_uint(f);
    u += 0x7fffu + ((u >> 16) & 1u);   // RNE
    return (u16)(u >> 16);
}
__device__ __forceinline__ float bf2f(u16 h) {
    return __uint_as_float(((unsigned)h) << 16);
}

__device__ __forceinline__ void gload_lds16(const void* g, void* l) {
    __builtin_amdgcn_global_load_lds((AS1 unsigned int*)(g),
                                     (AS3 unsigned int*)(l), 16, 0, 0);
}

// ---------------- stage 1: prep (W0/W1 cvt + Qt/E1 build) ----------------
__global__ void prep_kernel(const float* __restrict__ W0, const float* __restrict__ W1,
                            const float* __restrict__ x, const float* __restrict__ emb,
                            u16* __restrict__ W0b, u16* __restrict__ W1b,
                            u16* __restrict__ Qt, u16* __restrict__ E1) {
    int gid = blockIdx.x;
    if (gid < 4608) {                       // cvt W0 (4096 blocks) + W1 (512 blocks)
        int i = gid * 256 + threadIdx.x;
        const float* src; u16* dst; int j;
        if (i < 1048576) { src = W0; dst = W0b; j = i; }
        else             { src = W1; dst = W1b; j = i - 1048576; }
        float4 v = reinterpret_cast<const float4*>(src)[j];
        ushort4 o;
        o.x = f2bf(v.x); o.y = f2bf(v.y); o.z = f2bf(v.z); o.w = f2bf(v.w);
        reinterpret_cast<ushort4*>(dst)[j] = o;
    } else {                                // build Qt + E1: 1024 blocks x 4 n each
        int n = (gid - 4608) * 4 + (threadIdx.x >> 6);
        int lane = threadIdx.x & 63;
        int b = n >> 4, d = n & 15;
        int m0 = lane * 4;
        float4 xv = *reinterpret_cast<const float4*>(x + b * 256 + m0);
        ushort4 q;
        q.x = f2bf(xv.x * emb[(m0 + 0) * 16 + d]);
        q.y = f2bf(xv.y * emb[(m0 + 1) * 16 + d]);
        q.z = f2bf(xv.z * emb[(m0 + 2) * 16 + d]);
        q.w = f2bf(xv.w * emb[(m0 + 3) * 16 + d]);
        *reinterpret_cast<ushort4*>(Qt + n * 256 + m0) = q;
        // E1 pack: [ntile 16][wm 2][wn 2][fm 8][fn 8][lane 64][e 4]
        // h=m0..m0+3: wm=(m0>>7)&1, fm=(m0>>4)&7, sl=(m0>>2)&3, e=m0&3
        // n: ntile=n>>8, wn=(n>>7)&1, fn=(n>>4)&7, c=n&15; lane=sl*16+c
        int e1u4 = (((((n >> 8) * 2 + ((m0 >> 7) & 1)) * 2 + ((n >> 7) & 1)) * 8
                   + ((m0 >> 4) & 7)) * 8 + ((n >> 4) & 7)) * 64
                   + ((m0 >> 2) & 3) * 16 + (n & 15);
        *reinterpret_cast<ushort4*>(E1 + e1u4 * 4) = q;
    }
}

// ---------------- stage 2: layer 1 — 4 waves (1/SIMD), 128x128 wave tiles ----------------
// grid 1024 (8 xcd x 8 o x 16 nt), 256 thr. Block 256h x 256n, BK=64, 2 LDS bufs.
// acc[8][8] -> AGPRs; B-frags prefetched, A-frags streamed under the MFMA cluster.
__global__ __launch_bounds__(256, 1) void cin1_kernel(
    const u16* __restrict__ W0b, const u16* __restrict__ Qt, const u16* __restrict__ E1,
    const float* __restrict__ b0, u16* __restrict__ E2, float* __restrict__ S1)
{
    __shared__ __attribute__((aligned(16))) u16 ldsA[2][16384];  // [256 r][64 k] swz
    __shared__ __attribute__((aligned(16))) u16 ldsB[2][16384];
    __shared__ float part[2][256];

    const int tid = threadIdx.x, lane = tid & 63, w = tid >> 6;
    const int wm = w >> 1, wn = w & 1;
    const int bid = blockIdx.x;
    const int o = (bid & 7) * 8 + ((bid >> 3) & 7);   // 8 o's per XCD
    const int ntile = bid >> 6;                        // 0..15

    // staging: instr i covers rows i*32+(tid>>3); phys slot tid&7 holds logical (tid&7)^row&7
    const int srow = tid >> 3;
    const int sswz = ((tid & 7) ^ (srow & 7)) * 8;     // u16
    const u16* aSrc = W0b + (o * 256 + srow) * 256 + sswz;
    const u16* bSrc = Qt + (ntile * 256 + srow) * 256 + sswz;

    // frag read: row R = (wm|wn)*128 + f*16 + (lane&15); phys = (ks*4 + lane>>4) ^ (R&7);
    // R&7 = lane&7 (all other terms are multiples of 8) -> one constant per ks
    const int swz0 = (((lane >> 4) + 0) ^ (lane & 7)) * 8;
    const int swz1 = (((lane >> 4) + 4) ^ (lane & 7)) * 8;
    const int aRow = (wm * 128 + (lane & 15)) * 64;    // + fm*1024
    const int bRow = (wn * 128 + (lane & 15)) * 64;    // + fn*1024

    f32x4 zero = {0.f, 0.f, 0.f, 0.f};
    f32x4 acc[8][8];
#pragma unroll
    for (int fm = 0; fm < 8; ++fm)
#pragma unroll
        for (int fn = 0; fn < 8; ++fn) acc[fm][fn] = zero;

#define STAGE(kt, buf)                                                             \
    _Pragma("unroll")                                                              \
    for (int i_ = 0; i_ < 8; ++i_) {                                               \
        gload_lds16(aSrc + i_ * 8192 + (kt) * 64, &ldsA[buf][i_ * 2048 + tid * 8]); \
        gload_lds16(bSrc + i_ * 8192 + (kt) * 64, &ldsB[buf][i_ * 2048 + tid * 8]); \
    }

    // prologue: kt0 -> buf0, kt1 -> buf1
    STAGE(0, 0) STAGE(1, 1)
    asm volatile("s_waitcnt vmcnt(16)" ::: "memory");   // kt0 landed (kt1 in flight)
    __builtin_amdgcn_s_barrier();
    asm volatile("" ::: "memory");

#pragma unroll
    for (int kt = 0; kt < 4; ++kt) {
        const int cur = kt & 1;
        // B fragments first (16 b128), then stream A per-fm under the MFMA cluster
        bf16x8 bF[8][2];
#pragma unroll
        for (int fn = 0; fn < 8; ++fn) {
            bF[fn][0] = *reinterpret_cast<const bf16x8*>(&ldsB[cur][bRow + fn * 1024 + swz0]);
            bF[fn][1] = *reinterpret_cast<const bf16x8*>(&ldsB[cur][bRow + fn * 1024 + swz1]);
        }
#pragma unroll
        for (int fm = 0; fm < 8; ++fm) {
            bf16x8 a0 = *reinterpret_cast<const bf16x8*>(&ldsA[cur][aRow + fm * 1024 + swz0]);
            bf16x8 a1 = *reinterpret_cast<const bf16x8*>(&ldsA[cur][aRow + fm * 1024 + swz1]);
#pragma unroll
            for (int fn = 0; fn < 8; ++fn) {
                acc[fm][fn] = __builtin_amdgcn_mfma_f32_16x16x32_bf16(a0, bF[fn][0], acc[fm][fn], 0, 0, 0);
                acc[fm][fn] = __builtin_amdgcn_mfma_f32_16x16x32_bf16(a1, bF[fn][1], acc[fm][fn], 0, 0, 0);
            }
        }
        if (kt < 3) {
            asm volatile("s_waitcnt lgkmcnt(0)" ::: "memory");   // this buf fully consumed
            __builtin_amdgcn_s_barrier();                        // ... by ALL waves
            asm volatile("" ::: "memory");
            if (kt < 2) STAGE(kt + 2, cur)                       // refill the freed buffer
            if (kt < 2) asm volatile("s_waitcnt vmcnt(16)" ::: "memory");  // kt+1 landed
            else        asm volatile("s_waitcnt vmcnt(0)" ::: "memory");   // kt3 landed
            __builtin_amdgcn_s_barrier();
            asm volatile("" ::: "memory");
        }
    }
#undef STAGE

    // epilogue: X1[o][n] = sum_h Q[h][n]*G[h][n]; E1 pre-packed per fragment
    float psum[8] = {0.f, 0.f, 0.f, 0.f, 0.f, 0.f, 0.f, 0.f};
    const u16* eb = E1 + (((ntile * 2 + wm) * 2 + wn) * 16384) + lane * 4;
#pragma unroll
    for (int fm = 0; fm < 8; ++fm)
#pragma unroll
        for (int fn = 0; fn < 8; ++fn) {
            ushort4 wv = *reinterpret_cast<const ushort4*>(eb + (fm * 8 + fn) * 256);
            psum[fn] += bf2f(wv.x) * acc[fm][fn][0] + bf2f(wv.y) * acc[fm][fn][1]
                      + bf2f(wv.z) * acc[fm][fn][2] + bf2f(wv.w) * acc[fm][fn][3];
        }
#pragma unroll
    for (int fn = 0; fn < 8; ++fn) {
        float p = psum[fn];
        p += __shfl_xor(p, 16);
        p += __shfl_xor(p, 32);
        if (lane < 16) part[wm][wn * 128 + fn * 16 + lane] = p;
    }
    __syncthreads();
    {
        const int nl = tid;
        float v = part[0][nl] + part[1][nl] + b0[o];
        float r = fmaxf(v, 0.0f);
        const int n = ntile * 256 + nl;
        if (o < 32) {
            E2[(n >> 4) * 512 + (n & 15) * 32 + o] = f2bf(r);   // [n/16][c 16][h 32]
        } else {
            float s = r;
            s += __shfl_xor(s, 1); s += __shfl_xor(s, 2);
            s += __shfl_xor(s, 4); s += __shfl_xor(s, 8);
            if ((n & 15) == 0) S1[(n >> 4) * 32 + (o - 32)] = s;
        }
    }
}

// ---------------- stage 3: layer 2 (proven structure, unchanged) ----------------
__global__ __launch_bounds__(256, 4) void cin2_kernel(
    const u16* __restrict__ W1b, const u16* __restrict__ Qt, const u16* __restrict__ E2,
    const float* __restrict__ b1, float* __restrict__ S2)
{
    __shared__ __attribute__((aligned(16))) u16 As[3][4096];   // 128r x 32k
    __shared__ __attribute__((aligned(16))) u16 Bs[3][4096];
    __shared__ float part[2][2][128];

    const int tid = threadIdx.x, lane = tid & 63, w = tid >> 6;
    const int wh = w >> 1, wn = w & 1;
    const int bid = blockIdx.x;
    const int g8 = bid & 7, rest = bid >> 3;     // 0..63
    const int og = g8 * 2 + (rest & 1);          // 0..15
    const int ntile = rest >> 1;                 // 0..31

    const int rl = lane >> 2;
    const int sw = ((lane & 3) ^ ((rl + (rl >> 2)) & 3)) << 3;
    const u16* aS0 = W1b + (og * 128 + (w * 2 + 0) * 16 + rl) * 256 + sw;
    const u16* aS1 = W1b + (og * 128 + (w * 2 + 1) * 16 + rl) * 256 + sw;
    const u16* bS0 = Qt + (ntile * 128 + (w * 2 + 0) * 16 + rl) * 256 + sw;
    const u16* bS1 = Qt + (ntile * 128 + (w * 2 + 1) * 16 + rl) * 256 + sw;
    const int ldsI0 = (w * 2 + 0) * 512, ldsI1 = (w * 2 + 1) * 512;

    const int rbA = wh * 64 + (lane & 15);
    const int rbB = wn * 64 + (lane & 15);
    const int sl = lane >> 4;
    const int aOff = rbA * 32 + ((sl ^ ((rbA + (rbA >> 2)) & 3)) << 3);
    const int bOff = rbB * 32 + ((sl ^ ((rbB + (rbB >> 2)) & 3)) << 3);

    f32x4 zero = {0.f, 0.f, 0.f, 0.f};
    f32x4 acc[4][4];
#pragma unroll
    for (int f = 0; f < 4; ++f)
#pragma unroll
        for (int gg = 0; gg < 4; ++gg) acc[f][gg] = zero;

    auto stage = [&](int kc, int bb) {
        int ko = kc * 32;
        gload_lds16(aS0 + ko, &As[bb][ldsI0]);
        gload_lds16(aS1 + ko, &As[bb][ldsI1]);
        gload_lds16(bS0 + ko, &Bs[bb][ldsI0]);
        gload_lds16(bS1 + ko, &Bs[bb][ldsI1]);
    };

    stage(0, 0); stage(1, 1);
#pragma unroll
    for (int kc = 0; kc < 8; ++kc) {
        if (kc < 7) asm volatile("s_waitcnt vmcnt(4)" ::: "memory");
        else        asm volatile("s_waitcnt vmcnt(0)" ::: "memory");
        __builtin_amdgcn_s_barrier();
        asm volatile("" ::: "memory");
        if (kc < 6) stage(kc + 2, (kc + 2) % 3);
        const u16* Ab = &As[kc % 3][0];
        const u16* Bb = &Bs[kc % 3][0];
        bf16x8 a[4], b[4];
#pragma unroll
        for (int f = 0; f < 4; ++f)
            a[f] = *reinterpret_cast<const bf16x8*>(Ab + aOff + f * 512);
#pragma unroll
        for (int gg = 0; gg < 4; ++gg)
            b[gg] = *reinterpret_cast<const bf16x8*>(Bb + bOff + gg * 512);
        __builtin_amdgcn_s_setprio(1);
#pragma unroll
        for (int f = 0; f < 4; ++f)
#pragma unroll
            for (int gg = 0; gg < 4; ++gg)
                acc[f][gg] = __builtin_amdgcn_mfma_f32_16x16x32_bf16(a[f], b[gg], acc[f][gg], 0, 0, 0);
        __builtin_amdgcn_s_setprio(0);
    }

    float psum[2][4] = {{0.f,0.f,0.f,0.f},{0.f,0.f,0.f,0.f}};
    const u16* eb = E2 + (ntile * 2 + wn) * 2048 + (lane & 15) * 32 + (lane >> 4) * 4;
#pragma unroll
    for (int f = 0; f < 4; ++f)
#pragma unroll
        for (int gg = 0; gg < 4; ++gg) {
            ushort4 wv = *reinterpret_cast<const ushort4*>(eb + gg * 512 + (f & 1) * 16);
            psum[f >> 1][gg] += bf2f(wv.x) * acc[f][gg][0] + bf2f(wv.y) * acc[f][gg][1]
                              + bf2f(wv.z) * acc[f][gg][2] + bf2f(wv.w) * acc[f][gg][3];
        }
#pragma unroll
    for (int ol = 0; ol < 2; ++ol)
#pragma unroll
        for (int gg = 0; gg < 4; ++gg) {
            float p = psum[ol][gg];
            p += __shfl_xor(p, 16);
            p += __shfl_xor(p, 32);
            if (lane < 16) part[wh][ol][wn * 64 + gg * 16 + lane] = p;
        }
    __syncthreads();
    if (tid < 128) {
        const int nl = tid;
        const int n = ntile * 128 + nl;
#pragma unroll
        for (int o4 = 0; o4 < 4; ++o4) {
            const int oo = og * 4 + o4;
            float v = part[o4 >> 1][o4 & 1][nl] + b1[oo];
            float r = fmaxf(v, 0.0f);
            float s = r;
            s += __shfl_xor(s, 1); s += __shfl_xor(s, 2);
            s += __shfl_xor(s, 4); s += __shfl_xor(s, 8);
            if ((nl & 15) == 0) S2[(n >> 4) * 64 + oo] = s;
        }
    }
}

// ---------------- stage 4: final FC ----------------
__global__ void final_fc_kernel(const float* __restrict__ S1, const float* __restrict__ S2,
                                const float* __restrict__ fcW, const float* __restrict__ fcb,
                                float* __restrict__ out) {
    int b = threadIdx.x;   // 256
    float a0 = fcb[0], a1 = fcb[1];
#pragma unroll 8
    for (int c = 0; c < 32; ++c) {
        float v = S1[b * 32 + c];
        a0 += v * fcW[c]; a1 += v * fcW[96 + c];
    }
#pragma unroll 8
    for (int c = 0; c < 64; ++c) {
        float v = S2[b * 64 + c];
        a0 += v * fcW[32 + c]; a1 += v * fcW[96 + 32 + c];
    }
    out[b * 2 + 0] = a0;
    out[b * 2 + 1] = a1;
}

extern "C" void kernel_launch(void* const* d_in, const int* in_sizes, int n_in,
                              void* d_out, int out_size, void* d_ws, size_t ws_size,
                              hipStream_t stream) {
    const float* x   = (const float*)d_in[0];
    const float* emb = (const float*)d_in[1];
    const float* W0  = (const float*)d_in[2];
    const float* b0  = (const float*)d_in[3];
    const float* W1  = (const float*)d_in[4];
    const float* b1  = (const float*)d_in[5];
    const float* fcW = (const float*)d_in[6];
    const float* fcb = (const float*)d_in[7];
    float* out = (float*)d_out;

    char* ws = (char*)d_ws;
    u16*   W0b = (u16*)(ws);                 //  8,388,608 B
    u16*   W1b = (u16*)(ws + 8388608);       //  1,048,576 B
    u16*   Qt  = (u16*)(ws + 9437184);       //  2,097,152 B
    u16*   E1  = (u16*)(ws + 11534336);      //  2,097,152 B
    u16*   E2  = (u16*)(ws + 13631488);      //    262,144 B
    float* S1  = (float*)(ws + 13893632);    //     32,768 B
    float* S2  = (float*)(ws + 13926400);    //     65,536 B

    prep_kernel<<<5632, 256, 0, stream>>>(W0, W1, x, emb, W0b, W1b, Qt, E1);
    cin1_kernel<<<1024, 256, 0, stream>>>(W0b, Qt, E1, b0, E2, S1);
    cin2_kernel<<<512, 256, 0, stream>>>(W1b, Qt, E2, b1, S2);
    final_fc_kernel<<<1, 256, 0, stream>>>(S1, S2, fcW, fcb, out);
}

// Round 11
// 77.888 us; speedup vs baseline: 2.6195x; 1.0781x over previous
//
#include <hip/hip_runtime.h>

typedef unsigned short u16;
typedef short bf16x8 __attribute__((ext_vector_type(8)));
typedef float f32x4 __attribute__((ext_vector_type(4)));

#define AS1 __attribute__((address_space(1)))
#define AS3 __attribute__((address_space(3)))

__device__ __forceinline__ u16 f2bf(float f) {
    unsigned u = __float_as_uint(f);
    u += 0x7fffu + ((u >> 16) & 1u);   // RNE
    return (u16)(u >> 16);
}
__device__ __forceinline__ float bf2f(u16 h) {
    return __uint_as_float(((unsigned)h) << 16);
}

__device__ __forceinline__ void gload_lds16(const void* g, void* l) {
    __builtin_amdgcn_global_load_lds((AS1 unsigned int*)(g),
                                     (AS3 unsigned int*)(l), 16, 0, 0);
}

// ---------------- stage 1: prep (W0/W1 cvt + Qt/E1 build) ----------------
__global__ void prep_kernel(const float* __restrict__ W0, const float* __restrict__ W1,
                            const float* __restrict__ x, const float* __restrict__ emb,
                            u16* __restrict__ W0b, u16* __restrict__ W1b,
                            u16* __restrict__ Qt, u16* __restrict__ E1) {
    int gid = blockIdx.x;
    if (gid < 4608) {                       // cvt W0 (4096 blocks) + W1 (512 blocks)
        int i = gid * 256 + threadIdx.x;
        const float* src; u16* dst; int j;
        if (i < 1048576) { src = W0; dst = W0b; j = i; }
        else             { src = W1; dst = W1b; j = i - 1048576; }
        float4 v = reinterpret_cast<const float4*>(src)[j];
        ushort4 o;
        o.x = f2bf(v.x); o.y = f2bf(v.y); o.z = f2bf(v.z); o.w = f2bf(v.w);
        reinterpret_cast<ushort4*>(dst)[j] = o;
    } else {                                // build Qt + E1: 1024 blocks x 4 n each
        int n = (gid - 4608) * 4 + (threadIdx.x >> 6);
        int lane = threadIdx.x & 63;
        int b = n >> 4, d = n & 15;
        int m0 = lane * 4;
        float4 xv = *reinterpret_cast<const float4*>(x + b * 256 + m0);
        ushort4 q;
        q.x = f2bf(xv.x * emb[(m0 + 0) * 16 + d]);
        q.y = f2bf(xv.y * emb[(m0 + 1) * 16 + d]);
        q.z = f2bf(xv.z * emb[(m0 + 2) * 16 + d]);
        q.w = f2bf(xv.w * emb[(m0 + 3) * 16 + d]);
        *reinterpret_cast<ushort4*>(Qt + n * 256 + m0) = q;
        // E1 pack: [ntile 16][wm 2][wn 2][fm 8][fn 8][lane 64][e 4]
        int e1u4 = (((((n >> 8) * 2 + ((m0 >> 7) & 1)) * 2 + ((n >> 7) & 1)) * 8
                   + ((m0 >> 4) & 7)) * 8 + ((n >> 4) & 7)) * 64
                   + ((m0 >> 2) & 3) * 16 + (n & 15);
        *reinterpret_cast<ushort4*>(E1 + e1u4 * 4) = q;
    }
}

// ---------------- stage 2: layer 1 — 128x128 wave tiles, acc in AGPRs ----------------
// grid 1024 (8 xcd x 8 o x 16 nt), 256 thr = 4 waves (2wm x 2wn). Block 256h x 256n,
// BK=64, 2 LDS bufs. acc[8][8] forced to AGPRs via inline-asm "+a" (exactly 256 AGPR).
__global__ __launch_bounds__(256, 1) void cin1_kernel(
    const u16* __restrict__ W0b, const u16* __restrict__ Qt, const u16* __restrict__ E1,
    const float* __restrict__ b0, u16* __restrict__ E2, float* __restrict__ S1)
{
    __shared__ __attribute__((aligned(16))) u16 ldsA[2][16384];  // [256 r][64 k] swz
    __shared__ __attribute__((aligned(16))) u16 ldsB[2][16384];
    __shared__ float part[2][256];

    const int tid = threadIdx.x, lane = tid & 63, w = tid >> 6;
    const int wm = w >> 1, wn = w & 1;
    const int bid = blockIdx.x;
    const int o = (bid & 7) * 8 + ((bid >> 3) & 7);   // 8 o's per XCD
    const int ntile = bid >> 6;                        // 0..15

    // staging: instr i covers rows i*32+(tid>>3); phys slot tid&7 holds logical (tid&7)^(row&7)
    const int srow = tid >> 3;
    const int sswz = ((tid & 7) ^ (srow & 7)) * 8;     // u16
    const u16* aSrc = W0b + (o * 256 + srow) * 256 + sswz;
    const u16* bSrc = Qt + (ntile * 256 + srow) * 256 + sswz;

    // frag read: row R = (wm|wn)*128 + f*16 + (lane&15); phys = (ks*4 + lane>>4) ^ (R&7);
    // R&7 = lane&7 -> one constant per ks
    const int swz0 = (((lane >> 4) + 0) ^ (lane & 7)) * 8;
    const int swz1 = (((lane >> 4) + 4) ^ (lane & 7)) * 8;
    const int aRow = (wm * 128 + (lane & 15)) * 64;    // + fm*1024
    const int bRow = (wn * 128 + (lane & 15)) * 64;    // + fn*1024

    f32x4 zero = {0.f, 0.f, 0.f, 0.f};
    f32x4 acc[8][8];
#pragma unroll
    for (int fm = 0; fm < 8; ++fm)
#pragma unroll
        for (int fn = 0; fn < 8; ++fn) acc[fm][fn] = zero;

#define MFMA_A(accv, av, bv)                                                       \
    asm("v_mfma_f32_16x16x32_bf16 %0, %1, %2, %0" : "+a"(accv) : "v"(av), "v"(bv));

#define STAGE(kt, buf)                                                             \
    _Pragma("unroll")                                                              \
    for (int i_ = 0; i_ < 8; ++i_) {                                               \
        gload_lds16(aSrc + i_ * 8192 + (kt) * 64, &ldsA[buf][i_ * 2048 + tid * 8]); \
        gload_lds16(bSrc + i_ * 8192 + (kt) * 64, &ldsB[buf][i_ * 2048 + tid * 8]); \
    }

    // prologue: kt0 -> buf0, kt1 -> buf1
    STAGE(0, 0) STAGE(1, 1)
    asm volatile("s_waitcnt vmcnt(16)" ::: "memory");   // kt0 landed (kt1 in flight)
    __builtin_amdgcn_s_barrier();
    asm volatile("" ::: "memory");

#pragma unroll
    for (int kt = 0; kt < 4; ++kt) {
        const int cur = kt & 1;
        // B fragments first (16 b128), then stream A per-fm under the MFMA cluster
        bf16x8 bF[8][2];
#pragma unroll
        for (int fn = 0; fn < 8; ++fn) {
            bF[fn][0] = *reinterpret_cast<const bf16x8*>(&ldsB[cur][bRow + fn * 1024 + swz0]);
            bF[fn][1] = *reinterpret_cast<const bf16x8*>(&ldsB[cur][bRow + fn * 1024 + swz1]);
        }
#pragma unroll
        for (int fm = 0; fm < 8; ++fm) {
            bf16x8 a0 = *reinterpret_cast<const bf16x8*>(&ldsA[cur][aRow + fm * 1024 + swz0]);
            bf16x8 a1 = *reinterpret_cast<const bf16x8*>(&ldsA[cur][aRow + fm * 1024 + swz1]);
#pragma unroll
            for (int fn = 0; fn < 8; ++fn) {
                MFMA_A(acc[fm][fn], a0, bF[fn][0])
                MFMA_A(acc[fm][fn], a1, bF[fn][1])
            }
        }
        if (kt < 3) {
            asm volatile("s_waitcnt lgkmcnt(0)" ::: "memory");   // this buf fully consumed
            __builtin_amdgcn_s_barrier();                        // ... by ALL waves
            asm volatile("" ::: "memory");
            if (kt < 2) STAGE(kt + 2, cur)                       // refill the freed buffer
            if (kt < 2) asm volatile("s_waitcnt vmcnt(16)" ::: "memory");  // kt+1 landed
            else        asm volatile("s_waitcnt vmcnt(0)" ::: "memory");   // kt3 landed
            __builtin_amdgcn_s_barrier();
            asm volatile("" ::: "memory");
        }
    }
#undef STAGE
#undef MFMA_A

    // epilogue: X1[o][n] = sum_h Q[h][n]*G[h][n]; E1 pre-packed per fragment
    float psum[8] = {0.f, 0.f, 0.f, 0.f, 0.f, 0.f, 0.f, 0.f};
    const u16* eb = E1 + (((ntile * 2 + wm) * 2 + wn) * 16384) + lane * 4;
#pragma unroll
    for (int fm = 0; fm < 8; ++fm)
#pragma unroll
        for (int fn = 0; fn < 8; ++fn) {
            ushort4 wv = *reinterpret_cast<const ushort4*>(eb + (fm * 8 + fn) * 256);
            psum[fn] += bf2f(wv.x) * acc[fm][fn][0] + bf2f(wv.y) * acc[fm][fn][1]
                      + bf2f(wv.z) * acc[fm][fn][2] + bf2f(wv.w) * acc[fm][fn][3];
        }
#pragma unroll
    for (int fn = 0; fn < 8; ++fn) {
        float p = psum[fn];
        p += __shfl_xor(p, 16);
        p += __shfl_xor(p, 32);
        if (lane < 16) part[wm][wn * 128 + fn * 16 + lane] = p;
    }
    __syncthreads();
    {
        const int nl = tid;
        float v = part[0][nl] + part[1][nl] + b0[o];
        float r = fmaxf(v, 0.0f);
        const int n = ntile * 256 + nl;
        if (o < 32) {
            E2[(n >> 4) * 512 + (n & 15) * 32 + o] = f2bf(r);   // [n/16][c 16][h 32]
        } else {
            float s = r;
            s += __shfl_xor(s, 1); s += __shfl_xor(s, 2);
            s += __shfl_xor(s, 4); s += __shfl_xor(s, 8);
            if ((n & 15) == 0) S1[(n >> 4) * 32 + (o - 32)] = s;
        }
    }
}

// ---------------- stage 3: layer 2 (proven structure, unchanged) ----------------
__global__ __launch_bounds__(256, 4) void cin2_kernel(
    const u16* __restrict__ W1b, const u16* __restrict__ Qt, const u16* __restrict__ E2,
    const float* __restrict__ b1, float* __restrict__ S2)
{
    __shared__ __attribute__((aligned(16))) u16 As[3][4096];   // 128r x 32k
    __shared__ __attribute__((aligned(16))) u16 Bs[3][4096];
    __shared__ float part[2][2][128];

    const int tid = threadIdx.x, lane = tid & 63, w = tid >> 6;
    const int wh = w >> 1, wn = w & 1;
    const int bid = blockIdx.x;
    const int g8 = bid & 7, rest = bid >> 3;     // 0..63
    const int og = g8 * 2 + (rest & 1);          // 0..15
    const int ntile = rest >> 1;                 // 0..31

    const int rl = lane >> 2;
    const int sw = ((lane & 3) ^ ((rl + (rl >> 2)) & 3)) << 3;
    const u16* aS0 = W1b + (og * 128 + (w * 2 + 0) * 16 + rl) * 256 + sw;
    const u16* aS1 = W1b + (og * 128 + (w * 2 + 1) * 16 + rl) * 256 + sw;
    const u16* bS0 = Qt + (ntile * 128 + (w * 2 + 0) * 16 + rl) * 256 + sw;
    const u16* bS1 = Qt + (ntile * 128 + (w * 2 + 1) * 16 + rl) * 256 + sw;
    const int ldsI0 = (w * 2 + 0) * 512, ldsI1 = (w * 2 + 1) * 512;

    const int rbA = wh * 64 + (lane & 15);
    const int rbB = wn * 64 + (lane & 15);
    const int sl = lane >> 4;
    const int aOff = rbA * 32 + ((sl ^ ((rbA + (rbA >> 2)) & 3)) << 3);
    const int bOff = rbB * 32 + ((sl ^ ((rbB + (rbB >> 2)) & 3)) << 3);

    f32x4 zero = {0.f, 0.f, 0.f, 0.f};
    f32x4 acc[4][4];
#pragma unroll
    for (int f = 0; f < 4; ++f)
#pragma unroll
        for (int gg = 0; gg < 4; ++gg) acc[f][gg] = zero;

    auto stage = [&](int kc, int bb) {
        int ko = kc * 32;
        gload_lds16(aS0 + ko, &As[bb][ldsI0]);
        gload_lds16(aS1 + ko, &As[bb][ldsI1]);
        gload_lds16(bS0 + ko, &Bs[bb][ldsI0]);
        gload_lds16(bS1 + ko, &Bs[bb][ldsI1]);
    };

    stage(0, 0); stage(1, 1);
#pragma unroll
    for (int kc = 0; kc < 8; ++kc) {
        if (kc < 7) asm volatile("s_waitcnt vmcnt(4)" ::: "memory");
        else        asm volatile("s_waitcnt vmcnt(0)" ::: "memory");
        __builtin_amdgcn_s_barrier();
        asm volatile("" ::: "memory");
        if (kc < 6) stage(kc + 2, (kc + 2) % 3);
        const u16* Ab = &As[kc % 3][0];
        const u16* Bb = &Bs[kc % 3][0];
        bf16x8 a[4], b[4];
#pragma unroll
        for (int f = 0; f < 4; ++f)
            a[f] = *reinterpret_cast<const bf16x8*>(Ab + aOff + f * 512);
#pragma unroll
        for (int gg = 0; gg < 4; ++gg)
            b[gg] = *reinterpret_cast<const bf16x8*>(Bb + bOff + gg * 512);
        __builtin_amdgcn_s_setprio(1);
#pragma unroll
        for (int f = 0; f < 4; ++f)
#pragma unroll
            for (int gg = 0; gg < 4; ++gg)
                acc[f][gg] = __builtin_amdgcn_mfma_f32_16x16x32_bf16(a[f], b[gg], acc[f][gg], 0, 0, 0);
        __builtin_amdgcn_s_setprio(0);
    }

    float psum[2][4] = {{0.f,0.f,0.f,0.f},{0.f,0.f,0.f,0.f}};
    const u16* eb = E2 + (ntile * 2 + wn) * 2048 + (lane & 15) * 32 + (lane >> 4) * 4;
#pragma unroll
    for (int f = 0; f < 4; ++f)
#pragma unroll
        for (int gg = 0; gg < 4; ++gg) {
            ushort4 wv = *reinterpret_cast<const ushort4*>(eb + gg * 512 + (f & 1) * 16);
            psum[f >> 1][gg] += bf2f(wv.x) * acc[f][gg][0] + bf2f(wv.y) * acc[f][gg][1]
                              + bf2f(wv.z) * acc[f][gg][2] + bf2f(wv.w) * acc[f][gg][3];
        }
#pragma unroll
    for (int ol = 0; ol < 2; ++ol)
#pragma unroll
        for (int gg = 0; gg < 4; ++gg) {
            float p = psum[ol][gg];
            p += __shfl_xor(p, 16);
            p += __shfl_xor(p, 32);
            if (lane < 16) part[wh][ol][wn * 64 + gg * 16 + lane] = p;
        }
    __syncthreads();
    if (tid < 128) {
        const int nl = tid;
        const int n = ntile * 128 + nl;
#pragma unroll
        for (int o4 = 0; o4 < 4; ++o4) {
            const int oo = og * 4 + o4;
            float v = part[o4 >> 1][o4 & 1][nl] + b1[oo];
            float r = fmaxf(v, 0.0f);
            float s = r;
            s += __shfl_xor(s, 1); s += __shfl_xor(s, 2);
            s += __shfl_xor(s, 4); s += __shfl_xor(s, 8);
            if ((nl & 15) == 0) S2[(n >> 4) * 64 + oo] = s;
        }
    }
}

// ---------------- stage 4: final FC ----------------
__global__ void final_fc_kernel(const float* __restrict__ S1, const float* __restrict__ S2,
                                const float* __restrict__ fcW, const float* __restrict__ fcb,
                                float* __restrict__ out) {
    int b = threadIdx.x;   // 256
    float a0 = fcb[0], a1 = fcb[1];
#pragma unroll 8
    for (int c = 0; c < 32; ++c) {
        float v = S1[b * 32 + c];
        a0 += v * fcW[c]; a1 += v * fcW[96 + c];
    }
#pragma unroll 8
    for (int c = 0; c < 64; ++c) {
        float v = S2[b * 64 + c];
        a0 += v * fcW[32 + c]; a1 += v * fcW[96 + 32 + c];
    }
    out[b * 2 + 0] = a0;
    out[b * 2 + 1] = a1;
}

extern "C" void kernel_launch(void* const* d_in, const int* in_sizes, int n_in,
                              void* d_out, int out_size, void* d_ws, size_t ws_size,
                              hipStream_t stream) {
    const float* x   = (const float*)d_in[0];
    const float* emb = (const float*)d_in[1];
    const float* W0  = (const float*)d_in[2];
    const float* b0  = (const float*)d_in[3];
    const float* W1  = (const float*)d_in[4];
    const float* b1  = (const float*)d_in[5];
    const float* fcW = (const float*)d_in[6];
    const float* fcb = (const float*)d_in[7];
    float* out = (float*)d_out;

    char* ws = (char*)d_ws;
    u16*   W0b = (u16*)(ws);                 //  8,388,608 B
    u16*   W1b = (u16*)(ws + 8388608);       //  1,048,576 B
    u16*   Qt  = (u16*)(ws + 9437184);       //  2,097,152 B
    u16*   E1  = (u16*)(ws + 11534336);      //  2,097,152 B
    u16*   E2  = (u16*)(ws + 13631488);      //    262,144 B
    float* S1  = (float*)(ws + 13893632);    //     32,768 B
    float* S2  = (float*)(ws + 13926400);    //     65,536 B

    prep_kernel<<<5632, 256, 0, stream>>>(W0, W1, x, emb, W0b, W1b, Qt, E1);
    cin1_kernel<<<1024, 256, 0, stream>>>(W0b, Qt, E1, b0, E2, S1);
    cin2_kernel<<<512, 256, 0, stream>>>(W1b, Qt, E2, b1, S2);
    final_fc_kernel<<<1, 256, 0, stream>>>(S1, S2, fcW, fcb, out);
}